// Round 11
// baseline (817.945 us; speedup 1.0000x reference)
//
#include <hip/hip_runtime.h>

// ---------------------------------------------------------------------------
// RGCN (basis decomposition), 2 layers. N=50000, E=1e6, H=128, O=64, R=16.
// Round 11: round 10's barrier-free design had ONE bug: the aggregation
// m-tile loop was gated by nR (edge count) — but in agg, m = DST ROWS, not
// edges; rows 16..31 lost all contributions in chunks with <=16 real edges.
// Fix: agg m-tiles run unconditionally (k-dim pads are killed by P=0:
// ebuf memset 0xFF -> dloc=127 never matches tgt 0..31; when nR<=16, edges
// 16..31 get P=0 via the ~0 fill, so stale ys columns are inert).
// Design (unchanged from round 10):
//  - ZERO __syncthreads: each wave = independent worker (32 dst nodes x
//    OUT/4 cols), free-running over its block's 16 relation bins.
//  - GEMM1 A-frags straight from global (Xb + src*128 + ks*32 + quad*8);
//    4x col-split re-read absorbed by L2.
//  - P (indicator*norm) A-frags built in VALU from ebuf; no pmat LDS.
//  - ys (C->A transform) is wave-local LDS; same-wave in-order, no barrier.
// MFMA layouts identical to rounds 3-9 (passing).
// ---------------------------------------------------------------------------

typedef short bf16x8 __attribute__((ext_vector_type(8)));
typedef float f32x4 __attribute__((ext_vector_type(4)));

#define RELS 16
#define HDIM 128
#define DSTBLK 32
#define CHUNK 32

__device__ inline unsigned short f2bf(float f) {
  unsigned int u = __float_as_uint(f);
  unsigned int r = u + 0x7FFFu + ((u >> 16) & 1u);
  return (unsigned short)(r >> 16);
}

__global__ void cvt_bf16(const float* __restrict__ in, unsigned short* __restrict__ out, int n8) {
  int i = blockIdx.x * blockDim.x + threadIdx.x;
  if (i >= n8) return;
  float4 a = ((const float4*)in)[i * 2];
  float4 b = ((const float4*)in)[i * 2 + 1];
  uint4 o;
  o.x = (unsigned)f2bf(a.x) | ((unsigned)f2bf(a.y) << 16);
  o.y = (unsigned)f2bf(a.z) | ((unsigned)f2bf(a.w) << 16);
  o.z = (unsigned)f2bf(b.x) | ((unsigned)f2bf(b.y) << 16);
  o.w = (unsigned)f2bf(b.z) | ((unsigned)f2bf(b.w) << 16);
  ((uint4*)out)[i] = o;
}

// Wt[r][o][k] (bf16, transposed) = sum_b comp[r,b] * V[b,k,o]
__global__ void compute_w(const float* __restrict__ comp, const float* __restrict__ V,
                          unsigned short* __restrict__ Wt, int IO) {
  int idx = blockIdx.x * blockDim.x + threadIdx.x;
  if (idx >= RELS * IO * HDIM) return;
  int k = idx & (HDIM - 1);
  int o = (idx >> 7) % IO;
  int r = idx / (IO * HDIM);
  float s = 0.f;
#pragma unroll
  for (int b = 0; b < RELS; b++)
    s = fmaf(comp[r * RELS + b], V[(size_t)b * HDIM * IO + (size_t)k * IO + o], s);
  Wt[idx] = f2bf(s);
}

// direct global histogram: 1M atomics over 25008 counters (~40/counter)
__global__ void hist_bins(const int* __restrict__ dst, const int* __restrict__ etype,
                          int n, int* __restrict__ counts) {
  for (int i = blockIdx.x * blockDim.x + threadIdx.x; i < n; i += gridDim.x * blockDim.x)
    atomicAdd(&counts[(dst[i] >> 5) * RELS + etype[i]], 1);
}

// exclusive scan of counts padded to multiples of 16 (Hillis-Steele)
__global__ void scan_offsets(const int* __restrict__ counts, int* __restrict__ offsets, int nbins) {
  __shared__ int csum[256];
  const int t = threadIdx.x;
  const int CH = (nbins + 255) / 256;
  int lo = t * CH, hi = min(lo + CH, nbins);
  int s = 0;
  for (int i = lo; i < hi; i++) s += (counts[i] + 15) & ~15;
  csum[t] = s;
  __syncthreads();
#pragma unroll
  for (int d = 1; d < 256; d <<= 1) {
    int v = (t >= d) ? csum[t - d] : 0;
    __syncthreads();
    csum[t] += v;
    __syncthreads();
  }
  int run = (t == 0) ? 0 : csum[t - 1];
  for (int i = lo; i < hi; i++) {
    offsets[i] = run;
    run += (counts[i] + 15) & ~15;
  }
  if (lo < nbins && hi == nbins) offsets[nbins] = run;
}

// ebuf[p] = {src | dloc<<20, norm_bf16}; pad slots stay 0xFF (dloc=127).
__global__ void scatter_bins(const int* __restrict__ src, const int* __restrict__ dst,
                             const int* __restrict__ etype, const float* __restrict__ norm,
                             int n, const int* __restrict__ offsets, int* __restrict__ cursor,
                             uint2* __restrict__ ebuf) {
  for (int i = blockIdx.x * blockDim.x + threadIdx.x; i < n; i += gridDim.x * blockDim.x) {
    int d = dst[i];
    int b = (d >> 5) * RELS + etype[i];
    int p = offsets[b] + atomicAdd(&cursor[b], 1);
    ebuf[p] = make_uint2((unsigned)src[i] | ((unsigned)(d & 31) << 20),
                         (unsigned)f2bf(norm[i]));
  }
}

// Barrier-free layer: each wave owns (blockIdx's 32 dst nodes) x (its OUT/4
// column quarter) and free-runs over the block's 16 relation bins in 32-edge
// chunks. Per chunk: load ebuf slices -> GEMM1 with A-frags straight from
// global -> pack to wave-local ys^T -> VALU-built P-frags -> agg MFMA into
// persistent pacc. Epilogue: plain stores (+bias, optional ReLU+bf16).
template <int OUT, bool BF16_RELU_OUT>
__launch_bounds__(256, 4)
__global__ void rgcn_layer(const unsigned short* __restrict__ Xb,  // [N][128] bf16
                           const unsigned short* __restrict__ Wt,  // [R][OUT][128] bf16
                           const uint2* __restrict__ ebuf,
                           const int* __restrict__ offsets, const int* __restrict__ counts,
                           const float* __restrict__ bias, void* __restrict__ Hout,
                           int nNodes) {
  constexpr int NT = OUT / 64;  // n-tiles per wave: 2 (OUT=128) / 1 (OUT=64)
  __shared__ __align__(16) unsigned short ys[OUT][40];  // messages^T, wave-local cols

  const int t = threadIdx.x;
  const int w = t >> 6;
  const int lane = t & 63;
  const int quad = lane >> 4;
  const int l16 = lane & 15;
  const int nodeBase = blockIdx.x * DSTBLK;
  const int binBase = blockIdx.x * RELS;
  const int colBase = w * (OUT / 4);

  // zero own ys slice (NaN hygiene; wave-local -> no barrier)
  {
    uint4* yz = (uint4*)&ys[colBase][0];
    for (int i = lane; i < (OUT / 4) * 5; i += 64) yz[i] = make_uint4(0, 0, 0, 0);
  }

  f32x4 pacc[2][NT] = {};  // persistent dst accumulator (rows mt*16+quad*4+reg)

  for (int r = 0; r < RELS; r++) {
    const int start = offsets[binBase + r];
    const int binEnd = offsets[binBase + r + 1];
    if (start >= binEnd) continue;
    const int realEnd = start + counts[binBase + r];

    // W fragments for this relation (register-resident for the bin)
    const unsigned short* Wr = Wt + (size_t)r * OUT * HDIM;
    bf16x8 wf[4][NT];
#pragma unroll
    for (int ks = 0; ks < 4; ks++)
#pragma unroll
      for (int nt = 0; nt < NT; nt++)
        wf[ks][nt] = *(const bf16x8*)(Wr + (size_t)(colBase + nt * 16 + l16) * HDIM + ks * 32 + quad * 8);

    for (int base = start; base < binEnd; base += CHUNK) {
      const int nR = min(CHUNK, realEnd - base);  // real edge rows (>=1)
      const int avail = binEnd - base;            // in-bin entries (mult of 16)
      const bool upper = avail > 16;              // entries 16..31 in this bin

      // ---- ebuf edge-slice for P (edges quad*8 .. quad*8+7) ----
      uint4 q01, q23, q45, q67;
      if (quad * 8 < avail) {  // quads 0,1 always; 2,3 iff upper
        const uint4* eb = (const uint4*)(ebuf + base + quad * 8);
        q01 = eb[0]; q23 = eb[1]; q45 = eb[2]; q67 = eb[3];
      } else {
        q01 = q23 = q45 = q67 = make_uint4(~0u, ~0u, ~0u, ~0u);  // dloc=127 -> P=0
      }
      // ---- ebuf row entries for A (rows l16, 16+l16) ----
      uint2 er0 = ebuf[base + l16];
      uint2 er1 = upper ? ebuf[base + 16 + l16] : make_uint2(0u, 0u);

      // ---- GEMM1: Y = X[src] @ W_r, A-frags straight from global ----
      // (here m = EDGE rows -> gating by nR is correct; pad rows clamp to
      //  src 0 and their ys columns are killed by P=0 in agg)
#pragma unroll
      for (int mt = 0; mt < 2; mt++) {
        if (mt * 16 < nR) {  // wave-uniform
          unsigned w0 = mt ? er1.x : er0.x;
          int row = mt * 16 + l16;
          size_t s = (row < nR) ? (size_t)(w0 & 0xFFFFFu) : 0;  // clamp pad rows
          const unsigned short* xr = Xb + s * HDIM + quad * 8;
          f32x4 dacc[NT] = {};
#pragma unroll
          for (int ks = 0; ks < 4; ks++) {
            bf16x8 a = *(const bf16x8*)(xr + ks * 32);
#pragma unroll
            for (int nt = 0; nt < NT; nt++)
              dacc[nt] = __builtin_amdgcn_mfma_f32_16x16x32_bf16(a, wf[ks][nt], dacc[nt], 0, 0, 0);
          }
#pragma unroll
          for (int nt = 0; nt < NT; nt++) {
            uint2 pk;
            pk.x = (unsigned)f2bf(dacc[nt][0]) | ((unsigned)f2bf(dacc[nt][1]) << 16);
            pk.y = (unsigned)f2bf(dacc[nt][2]) | ((unsigned)f2bf(dacc[nt][3]) << 16);
            *(uint2*)&ys[colBase + nt * 16 + l16][mt * 16 + quad * 4] = pk;
          }
        }
      }

      // ---- agg: pacc += P @ Y; P A-frags built in VALU ----
      // B-frags: edges quad*8..+7 of own columns (same-wave in-order LDS RAW)
      bf16x8 bfv[NT];
#pragma unroll
      for (int nt = 0; nt < NT; nt++)
        bfv[nt] = *(const bf16x8*)&ys[colBase + nt * 16 + l16][quad * 8];

      // ROUND-11 FIX: m here = DST ROWS (always 0..31 live) — no nR gate.
      // k-dim (edges) pads carry P=0, so no gating is needed at all.
#pragma unroll
      for (int mt = 0; mt < 2; mt++) {
        const unsigned tgt = (unsigned)(mt * 16 + l16);
        union { unsigned u[4]; bf16x8 v; } pf;
        // entry pair (w0,w1),(w0,w1) per uint4; dloc=(w0>>20)&127; norm=w1&0xFFFF
        pf.u[0] = ((((q01.x >> 20) & 127u) == tgt) ? (q01.y & 0xFFFFu) : 0u) |
                  (((((q01.z >> 20) & 127u) == tgt) ? (q01.w & 0xFFFFu) : 0u) << 16);
        pf.u[1] = ((((q23.x >> 20) & 127u) == tgt) ? (q23.y & 0xFFFFu) : 0u) |
                  (((((q23.z >> 20) & 127u) == tgt) ? (q23.w & 0xFFFFu) : 0u) << 16);
        pf.u[2] = ((((q45.x >> 20) & 127u) == tgt) ? (q45.y & 0xFFFFu) : 0u) |
                  (((((q45.z >> 20) & 127u) == tgt) ? (q45.w & 0xFFFFu) : 0u) << 16);
        pf.u[3] = ((((q67.x >> 20) & 127u) == tgt) ? (q67.y & 0xFFFFu) : 0u) |
                  (((((q67.z >> 20) & 127u) == tgt) ? (q67.w & 0xFFFFu) : 0u) << 16);
#pragma unroll
        for (int nt = 0; nt < NT; nt++)
          pacc[mt][nt] = __builtin_amdgcn_mfma_f32_16x16x32_bf16(pf.v, bfv[nt], pacc[mt][nt], 0, 0, 0);
      }
    }
  }

  // epilogue: each (node, col) owned by exactly one lane -> plain stores
#pragma unroll
  for (int mt = 0; mt < 2; mt++) {
#pragma unroll
    for (int reg = 0; reg < 4; reg++) {
      int node = nodeBase + mt * 16 + quad * 4 + reg;
      if (node < nNodes) {
#pragma unroll
        for (int nt = 0; nt < NT; nt++) {
          int col = colBase + nt * 16 + l16;
          float v = pacc[mt][nt][reg] + bias[col];
          if constexpr (BF16_RELU_OUT)
            ((unsigned short*)Hout)[(size_t)node * OUT + col] = f2bf(fmaxf(v, 0.f));
          else
            ((float*)Hout)[(size_t)node * OUT + col] = v;
        }
      }
    }
  }
}

extern "C" void kernel_launch(void* const* d_in, const int* in_sizes, int n_in,
                              void* d_out, int out_size, void* d_ws, size_t ws_size,
                              hipStream_t stream) {
  const int*   src   = (const int*)d_in[1];
  const int*   dst   = (const int*)d_in[2];
  const int*   etype = (const int*)d_in[3];
  const float* norm  = (const float*)d_in[4];
  const float* emb   = (const float*)d_in[5];
  const float* V1    = (const float*)d_in[6];
  const float* comp1 = (const float*)d_in[7];
  const float* bias1 = (const float*)d_in[8];
  const float* V2    = (const float*)d_in[9];
  const float* comp2 = (const float*)d_in[10];
  const float* bias2 = (const float*)d_in[11];
  float* out = (float*)d_out;

  const int N = in_sizes[0];  // 50000
  const int E = in_sizes[1];  // 1000000
  const int H = 128, O = 64;
  const int NB = (N + DSTBLK - 1) / DSTBLK;  // 1563
  const int NBINS = NB * RELS;               // 25008
  const int EPAD_MAX = E + NBINS * 16 + 64;  // +64: tail-read slack

  char* ws = (char*)d_ws;
  size_t off = 0;
  auto alloc = [&](size_t bytes) -> void* {
    void* p = ws + off;
    off += (bytes + 255) & ~(size_t)255;
    return p;
  };
  unsigned short* W1t  = (unsigned short*)alloc(sizeof(short) * RELS * H * H);
  unsigned short* W2t  = (unsigned short*)alloc(sizeof(short) * RELS * O * H);
  unsigned short* embh = (unsigned short*)alloc(sizeof(short) * (size_t)N * H);
  unsigned short* h1b  = (unsigned short*)alloc(sizeof(short) * (size_t)N * H);
  uint2* ebuf = (uint2*)alloc(sizeof(uint2) * EPAD_MAX);
  int* counts  = (int*)alloc(sizeof(int) * NBINS);
  int* cursor  = (int*)alloc(sizeof(int) * NBINS);
  int* offsets = (int*)alloc(sizeof(int) * (NBINS + 1));

  hipMemsetAsync(counts, 0, sizeof(int) * NBINS, stream);
  hipMemsetAsync(cursor, 0, sizeof(int) * NBINS, stream);
  hipMemsetAsync(ebuf, 0xFF, sizeof(uint2) * EPAD_MAX, stream);  // pads: dloc=127

  cvt_bf16<<<((size_t)N * H / 8 + 255) / 256, 256, 0, stream>>>(emb, embh, N * H / 8);
  compute_w<<<(RELS * H * H + 255) / 256, 256, 0, stream>>>(comp1, V1, W1t, H);
  compute_w<<<(RELS * O * H + 255) / 256, 256, 0, stream>>>(comp2, V2, W2t, O);
  hist_bins<<<512, 256, 0, stream>>>(dst, etype, E, counts);
  scan_offsets<<<1, 256, 0, stream>>>(counts, offsets, NBINS);
  scatter_bins<<<1024, 256, 0, stream>>>(src, dst, etype, norm, E, offsets, cursor, ebuf);

  rgcn_layer<128, true><<<NB, 256, 0, stream>>>(embh, W1t, ebuf, offsets, counts, bias1, (void*)h1b, N);
  rgcn_layer<64, false><<<NB, 256, 0, stream>>>(h1b, W2t, ebuf, offsets, counts, bias2, (void*)out, N);
}

// Round 12
// 536.443 us; speedup vs baseline: 1.5248x; 1.5248x over previous
//
#include <hip/hip_runtime.h>

// ---------------------------------------------------------------------------
// RGCN (basis decomposition), 2 layers. N=50000, E=1e6, H=128, O=64, R=16.
// Round 12: hybrid of the two proven structures.
//  - Round 9 (140us L1): shared double-buffered xs in LDS (amortizes the
//    scattered gather across 4 waves), ONE barrier/chunk, in-phase prefetch
//    (ebuf loads before GEMM1, gathers between GEMM1 and agg, xs writes
//    before the barrier; no cross-barrier register liveness).
//  - Round 11 (correctness-proven): P(indicator*norm) A-frags built in VALU
//    from uint4 ebuf slices -> pmat LDS + handler logic deleted entirely
//    (round 11 measured: conflicts 1.08e7 -> 3.9e6, no spill). Agg m-tiles
//    ungated (m = dst rows; k-pads killed by P=0 from 0xFF ebuf fill).
//  - LDS 40.4K -> 27.6K => 4 blocks/CU; DSTBLK 64 -> grid 782 <= 1024
//    residency slots (single round). compute_w fused to one launch.
// Round 11's failure mode (per-wave global A-loads) is reverted.
// ---------------------------------------------------------------------------

typedef short bf16x8 __attribute__((ext_vector_type(8)));
typedef float f32x4 __attribute__((ext_vector_type(4)));

#define RELS 16
#define HDIM 128
#define DSTBLK 64
#define MT_P 4    // DSTBLK/16 dst-row tiles
#define CHUNK 32

__device__ inline unsigned short f2bf(float f) {
  unsigned int u = __float_as_uint(f);
  unsigned int r = u + 0x7FFFu + ((u >> 16) & 1u);
  return (unsigned short)(r >> 16);
}

__global__ void cvt_bf16(const float* __restrict__ in, unsigned short* __restrict__ out, int n8) {
  int i = blockIdx.x * blockDim.x + threadIdx.x;
  if (i >= n8) return;
  float4 a = ((const float4*)in)[i * 2];
  float4 b = ((const float4*)in)[i * 2 + 1];
  uint4 o;
  o.x = (unsigned)f2bf(a.x) | ((unsigned)f2bf(a.y) << 16);
  o.y = (unsigned)f2bf(a.z) | ((unsigned)f2bf(a.w) << 16);
  o.z = (unsigned)f2bf(b.x) | ((unsigned)f2bf(b.y) << 16);
  o.w = (unsigned)f2bf(b.z) | ((unsigned)f2bf(b.w) << 16);
  ((uint4*)out)[i] = o;
}

// Fused W1+W2: Wt[r][o][k] (bf16, transposed) = sum_b comp[r,b] * V[b,k,o]
__global__ void compute_w2(const float* __restrict__ comp1, const float* __restrict__ V1,
                           const float* __restrict__ comp2, const float* __restrict__ V2,
                           unsigned short* __restrict__ W1t, unsigned short* __restrict__ W2t) {
  int idx = blockIdx.x * blockDim.x + threadIdx.x;
  const int PER_R = HDIM * (HDIM + 64);  // 24576
  if (idx >= RELS * PER_R) return;
  int r = idx / PER_R;
  int rem = idx - r * PER_R;
  if (rem < HDIM * HDIM) {
    int o = rem >> 7, k = rem & 127;
    float s = 0.f;
#pragma unroll
    for (int b = 0; b < RELS; b++)
      s = fmaf(comp1[r * RELS + b], V1[(size_t)b * HDIM * HDIM + (size_t)k * HDIM + o], s);
    W1t[(size_t)r * HDIM * HDIM + rem] = f2bf(s);
  } else {
    int rr = rem - HDIM * HDIM;
    int o = rr >> 7, k = rr & 127;
    float s = 0.f;
#pragma unroll
    for (int b = 0; b < RELS; b++)
      s = fmaf(comp2[r * RELS + b], V2[(size_t)b * HDIM * 64 + (size_t)k * 64 + o], s);
    W2t[(size_t)r * 64 * HDIM + rr] = f2bf(s);
  }
}

// direct global histogram: 1M atomics over 12512 counters (~80/counter)
__global__ void hist_bins(const int* __restrict__ dst, const int* __restrict__ etype,
                          int n, int* __restrict__ counts) {
  for (int i = blockIdx.x * blockDim.x + threadIdx.x; i < n; i += gridDim.x * blockDim.x)
    atomicAdd(&counts[(dst[i] >> 6) * RELS + etype[i]], 1);
}

// exclusive scan of counts padded to multiples of 16 (Hillis-Steele)
__global__ void scan_offsets(const int* __restrict__ counts, int* __restrict__ offsets, int nbins) {
  __shared__ int csum[256];
  const int t = threadIdx.x;
  const int CH = (nbins + 255) / 256;
  int lo = t * CH, hi = min(lo + CH, nbins);
  int s = 0;
  for (int i = lo; i < hi; i++) s += (counts[i] + 15) & ~15;
  csum[t] = s;
  __syncthreads();
#pragma unroll
  for (int d = 1; d < 256; d <<= 1) {
    int v = (t >= d) ? csum[t - d] : 0;
    __syncthreads();
    csum[t] += v;
    __syncthreads();
  }
  int run = (t == 0) ? 0 : csum[t - 1];
  for (int i = lo; i < hi; i++) {
    offsets[i] = run;
    run += (counts[i] + 15) & ~15;
  }
  if (lo < nbins && hi == nbins) offsets[nbins] = run;
}

// ebuf[p] = {src | dloc<<20, norm_bf16}; pad slots stay 0xFF (dloc decodes 127).
__global__ void scatter_bins(const int* __restrict__ src, const int* __restrict__ dst,
                             const int* __restrict__ etype, const float* __restrict__ norm,
                             int n, const int* __restrict__ offsets, int* __restrict__ cursor,
                             uint2* __restrict__ ebuf) {
  for (int i = blockIdx.x * blockDim.x + threadIdx.x; i < n; i += gridDim.x * blockDim.x) {
    int d = dst[i];
    int b = (d >> 6) * RELS + etype[i];
    int p = offsets[b] + atomicAdd(&cursor[b], 1);
    ebuf[p] = make_uint2((unsigned)src[i] | ((unsigned)(d & 63) << 20),
                         (unsigned)f2bf(norm[i]));
  }
}

// One block owns 64 dst nodes; walks its 16 relation bins in 32-edge chunks.
// One barrier/chunk; xs double-buffered. Phase k: load P-slices(k); prefetch
// ebuf(k+1); GEMM1(k) from xs[cb] -> wave-local ys; gathers(k+1); agg(k) with
// VALU-built P-frags; write xs[cb^1]; barrier. Wave w owns cols [w*OUT/4,+OUT/4).
template <int OUT, bool BF16_RELU_OUT>
__launch_bounds__(256, 4)
__global__ void rgcn_layer(const unsigned short* __restrict__ Xb,  // [N][128] bf16
                           const unsigned short* __restrict__ Wt,  // [R][OUT][128] bf16
                           const uint2* __restrict__ ebuf,
                           const int* __restrict__ offsets, const int* __restrict__ counts,
                           const float* __restrict__ bias, void* __restrict__ Hout,
                           int nNodes) {
  constexpr int NT = OUT / 64;  // 2 (OUT=128) or 1 (OUT=64)
  __shared__ __align__(16) unsigned short xs[2][CHUNK][136];  // shared gathered src rows
  __shared__ __align__(16) unsigned short ys[OUT][40];        // messages^T, wave-local cols

  const int t = threadIdx.x;
  const int w = t >> 6;
  const int lane = t & 63;
  const int quad = lane >> 4;
  const int l16 = lane & 15;
  const int r0 = t >> 4;   // gather rows r0, r0+16
  const int k8 = t & 15;   // gather 8-elem column piece
  const int nodeBase = blockIdx.x * DSTBLK;
  const int binBase = blockIdx.x * RELS;
  const int colBase = w * (OUT / 4);

  // zero own ys slice (wave-local, in-order); zero xs (NaN hygiene)
  {
    uint4* yz = (uint4*)&ys[colBase][0];
    for (int i = lane; i < (OUT / 4) * 5; i += 64) yz[i] = make_uint4(0, 0, 0, 0);
  }
  for (int i = t; i < 2 * CHUNK * 136 / 8; i += 256) ((uint4*)xs)[i] = make_uint4(0, 0, 0, 0);

  f32x4 pacc[MT_P][NT] = {};  // persistent dst accumulator

  // first nonempty bin
  int bin = 0, base = 0, binEnd = 0, realEnd = 0;
  for (; bin < RELS; bin++) {
    base = offsets[binBase + bin];
    binEnd = offsets[binBase + bin + 1];
    if (base < binEnd) { realEnd = base + counts[binBase + bin]; break; }
  }

  __syncthreads();  // zero-init visible before prologue gather writes

  // prologue: gather chunk 0 into xs[0] (full latency exposed once)
  if (bin < RELS) {
    int nR = min(CHUNK, realEnd - base);
    if (r0 < nR) {
      uint2 e = ebuf[base + r0];
      *(uint4*)&xs[0][r0][k8 * 8] = *(const uint4*)(Xb + (size_t)(e.x & 0xFFFFFu) * HDIM + k8 * 8);
    }
    if (16 + r0 < nR) {
      uint2 e = ebuf[base + 16 + r0];
      *(uint4*)&xs[0][16 + r0][k8 * 8] = *(const uint4*)(Xb + (size_t)(e.x & 0xFFFFFu) * HDIM + k8 * 8);
    }
  }
  __syncthreads();

  int cb = 0;
  int curRel = -1;
  bf16x8 wf[4][NT];

  while (bin < RELS) {
    const int nRows = min(CHUNK, realEnd - base);
    const int avail = binEnd - base;  // in-bin slots this chunk (16 or >=32)

    // ---- P-slices for THIS chunk (edges quad*8..+7); latency under GEMM1 ----
    uint4 q01, q23, q45, q67;
    {
      const uint4* eb = (const uint4*)(ebuf + base + quad * 8);
      if (quad * 8 < avail) { q01 = eb[0]; q23 = eb[1]; q45 = eb[2]; q67 = eb[3]; }
      else q01 = q23 = q45 = q67 = make_uint4(~0u, ~0u, ~0u, ~0u);  // dloc=127 -> P=0
    }

    if (bin != curRel) {  // W fragments for this relation (register-resident)
      curRel = bin;
      const unsigned short* Wr = Wt + (size_t)bin * OUT * HDIM;
#pragma unroll
      for (int ks = 0; ks < 4; ks++)
#pragma unroll
        for (int nt = 0; nt < NT; nt++)
          wf[ks][nt] = *(const bf16x8*)(Wr + (size_t)(colBase + nt * 16 + l16) * HDIM + ks * 32 + quad * 8);
    }

    // next chunk coords (scalar)
    int nbin = bin, nbase = base + CHUNK, nbinEnd = binEnd, nrealEnd = realEnd;
    if (nbase >= binEnd) {
      for (nbin = bin + 1; nbin < RELS; nbin++) {
        nbase = offsets[binBase + nbin];
        nbinEnd = offsets[binBase + nbin + 1];
        if (nbase < nbinEnd) { nrealEnd = nbase + counts[binBase + nbin]; break; }
      }
    }
    const bool hasNext = nbin < RELS;
    const int nR = hasNext ? min(CHUNK, nrealEnd - nbase) : 0;

    // ---- prefetch next chunk's ebuf rows (latency under GEMM1) ----
    uint2 e0, e1;
    if (hasNext) {
      if (r0 < nR) e0 = ebuf[nbase + r0];
      if (16 + r0 < nR) e1 = ebuf[nbase + 16 + r0];
    }

    // ---- GEMM1: Y = xs[cb] @ W_r -> wave-local ys^T (m = edge rows) ----
#pragma unroll
    for (int mt = 0; mt < 2; mt++) {
      if (mt * 16 < nRows) {  // wave-uniform
        f32x4 dacc[NT] = {};
#pragma unroll
        for (int ks = 0; ks < 4; ks++) {
          bf16x8 a = *(const bf16x8*)&xs[cb][mt * 16 + l16][ks * 32 + quad * 8];
#pragma unroll
          for (int nt = 0; nt < NT; nt++)
            dacc[nt] = __builtin_amdgcn_mfma_f32_16x16x32_bf16(a, wf[ks][nt], dacc[nt], 0, 0, 0);
        }
#pragma unroll
        for (int nt = 0; nt < NT; nt++) {
          uint2 pk;
          pk.x = (unsigned)f2bf(dacc[nt][0]) | ((unsigned)f2bf(dacc[nt][1]) << 16);
          pk.y = (unsigned)f2bf(dacc[nt][2]) | ((unsigned)f2bf(dacc[nt][3]) << 16);
          *(uint2*)&ys[colBase + nt * 16 + l16][mt * 16 + quad * 4] = pk;
        }
      }
    }

    // ---- issue next chunk's gathers (latency under agg) ----
    uint4 g0, g1;
    if (hasNext) {
      if (r0 < nR) g0 = *(const uint4*)(Xb + (size_t)(e0.x & 0xFFFFFu) * HDIM + k8 * 8);
      if (16 + r0 < nR) g1 = *(const uint4*)(Xb + (size_t)(e1.x & 0xFFFFFu) * HDIM + k8 * 8);
    }

    // ---- agg: pacc += P @ Y; P A-frags in VALU (m = dst rows: NO gate) ----
    {
      bf16x8 bfv[NT];
#pragma unroll
      for (int nt = 0; nt < NT; nt++)
        bfv[nt] = *(const bf16x8*)&ys[colBase + nt * 16 + l16][quad * 8];
#pragma unroll
      for (int mt = 0; mt < MT_P; mt++) {
        const unsigned tgt = (unsigned)(mt * 16 + l16);
        union { unsigned u[4]; bf16x8 v; } pf;
        pf.u[0] = ((((q01.x >> 20) & 127u) == tgt) ? (q01.y & 0xFFFFu) : 0u) |
                  (((((q01.z >> 20) & 127u) == tgt) ? (q01.w & 0xFFFFu) : 0u) << 16);
        pf.u[1] = ((((q23.x >> 20) & 127u) == tgt) ? (q23.y & 0xFFFFu) : 0u) |
                  (((((q23.z >> 20) & 127u) == tgt) ? (q23.w & 0xFFFFu) : 0u) << 16);
        pf.u[2] = ((((q45.x >> 20) & 127u) == tgt) ? (q45.y & 0xFFFFu) : 0u) |
                  (((((q45.z >> 20) & 127u) == tgt) ? (q45.w & 0xFFFFu) : 0u) << 16);
        pf.u[3] = ((((q67.x >> 20) & 127u) == tgt) ? (q67.y & 0xFFFFu) : 0u) |
                  (((((q67.z >> 20) & 127u) == tgt) ? (q67.w & 0xFFFFu) : 0u) << 16);
#pragma unroll
        for (int nt = 0; nt < NT; nt++)
          pacc[mt][nt] = __builtin_amdgcn_mfma_f32_16x16x32_bf16(pf.v, bfv[nt], pacc[mt][nt], 0, 0, 0);
      }
    }

    // ---- write next chunk into the other xs buffer, then barrier ----
    if (hasNext) {
      if (r0 < nR) *(uint4*)&xs[cb ^ 1][r0][k8 * 8] = g0;
      if (16 + r0 < nR) *(uint4*)&xs[cb ^ 1][16 + r0][k8 * 8] = g1;
      __syncthreads();
    }

    bin = nbin; base = nbase; binEnd = nbinEnd; realEnd = nrealEnd;
    cb ^= 1;
  }

  // epilogue: each (node, col) owned by exactly one lane -> plain stores
#pragma unroll
  for (int mt = 0; mt < MT_P; mt++) {
#pragma unroll
    for (int reg = 0; reg < 4; reg++) {
      int node = nodeBase + mt * 16 + quad * 4 + reg;
      if (node < nNodes) {
#pragma unroll
        for (int nt = 0; nt < NT; nt++) {
          int col = colBase + nt * 16 + l16;
          float v = pacc[mt][nt][reg] + bias[col];
          if constexpr (BF16_RELU_OUT)
            ((unsigned short*)Hout)[(size_t)node * OUT + col] = f2bf(fmaxf(v, 0.f));
          else
            ((float*)Hout)[(size_t)node * OUT + col] = v;
        }
      }
    }
  }
}

extern "C" void kernel_launch(void* const* d_in, const int* in_sizes, int n_in,
                              void* d_out, int out_size, void* d_ws, size_t ws_size,
                              hipStream_t stream) {
  const int*   src   = (const int*)d_in[1];
  const int*   dst   = (const int*)d_in[2];
  const int*   etype = (const int*)d_in[3];
  const float* norm  = (const float*)d_in[4];
  const float* emb   = (const float*)d_in[5];
  const float* V1    = (const float*)d_in[6];
  const float* comp1 = (const float*)d_in[7];
  const float* bias1 = (const float*)d_in[8];
  const float* V2    = (const float*)d_in[9];
  const float* comp2 = (const float*)d_in[10];
  const float* bias2 = (const float*)d_in[11];
  float* out = (float*)d_out;

  const int N = in_sizes[0];  // 50000
  const int E = in_sizes[1];  // 1000000
  const int H = 128, O = 64;
  const int NB = (N + DSTBLK - 1) / DSTBLK;  // 782
  const int NBINS = NB * RELS;               // 12512
  const int EPAD_MAX = E + NBINS * 16 + 64;

  char* ws = (char*)d_ws;
  size_t off = 0;
  auto alloc = [&](size_t bytes) -> void* {
    void* p = ws + off;
    off += (bytes + 255) & ~(size_t)255;
    return p;
  };
  unsigned short* W1t  = (unsigned short*)alloc(sizeof(short) * RELS * H * H);
  unsigned short* W2t  = (unsigned short*)alloc(sizeof(short) * RELS * O * H);
  unsigned short* embh = (unsigned short*)alloc(sizeof(short) * (size_t)N * H);
  unsigned short* h1b  = (unsigned short*)alloc(sizeof(short) * (size_t)N * H);
  uint2* ebuf = (uint2*)alloc(sizeof(uint2) * EPAD_MAX);
  int* counts  = (int*)alloc(sizeof(int) * NBINS);
  int* cursor  = (int*)alloc(sizeof(int) * NBINS);
  int* offsets = (int*)alloc(sizeof(int) * (NBINS + 1));

  hipMemsetAsync(counts, 0, sizeof(int) * NBINS, stream);
  hipMemsetAsync(cursor, 0, sizeof(int) * NBINS, stream);
  hipMemsetAsync(ebuf, 0xFF, sizeof(uint2) * EPAD_MAX, stream);  // pads: dloc=127

  cvt_bf16<<<((size_t)N * H / 8 + 255) / 256, 256, 0, stream>>>(emb, embh, N * H / 8);
  compute_w2<<<(RELS * H * (H + O) + 255) / 256, 256, 0, stream>>>(comp1, V1, comp2, V2, W1t, W2t);
  hist_bins<<<512, 256, 0, stream>>>(dst, etype, E, counts);
  scan_offsets<<<1, 256, 0, stream>>>(counts, offsets, NBINS);
  scatter_bins<<<1024, 256, 0, stream>>>(src, dst, etype, norm, E, offsets, cursor, ebuf);

  rgcn_layer<128, true><<<NB, 256, 0, stream>>>(embh, W1t, ebuf, offsets, counts, bias1, (void*)h1b, N);
  rgcn_layer<64, false><<<NB, 256, 0, stream>>>(h1b, W2t, ebuf, offsets, counts, bias2, (void*)out, N);
}

// Round 13
// 505.193 us; speedup vs baseline: 1.6191x; 1.0619x over previous
//
#include <hip/hip_runtime.h>
#include <hip/hip_bf16.h>

// ---------------------------------------------------------------------------
// RGCN (basis decomposition), 2 layers. N=50000, E=1e6, H=128, O=64, R=16.
// Round 13: merge of measured-best mechanisms.
//  - Layer kernel = round 9's structure (best: 140us L1): shared double-
//    buffered xs, pmat maintained by handler lanes (clear-then-set, ~2 LDS
//    ops per 8 threads — round 12 proved the VALU-P alternative costs more:
//    VALU 32% vs 21%), ONE barrier/chunk, in-phase prefetch (ebuf loads
//    before GEMM1, gathers between GEMM1 and agg, LDS writes before the
//    barrier; no cross-barrier register liveness).
//  - VALU diet: ys packing via __float22bfloat162_rn (v_cvt_pk_bf16_f32),
//    norm stored as bf16 in ebuf so handlers write it raw.
//  - DSTBLK 64: grid 782 ~ 3.05 blocks/CU at 37.9KB LDS (L1) -> single
//    balanced residency round; L2 instantiation is exactly 32KB -> 4/CU.
//  - Preprocessing: no ebuf memset (guards by counts, proven in round 9);
//    cvt_bf16+compute_w fused into one launch; counts+cursor one memset.
// ---------------------------------------------------------------------------

typedef short bf16x8 __attribute__((ext_vector_type(8)));
typedef float f32x4 __attribute__((ext_vector_type(4)));

#define RELS 16
#define HDIM 128
#define DSTBLK 64
#define MT_P 4    // DSTBLK/16 dst-row tiles
#define CHUNK 32

__device__ inline unsigned short f2bf(float f) {
  unsigned int u = __float_as_uint(f);
  unsigned int r = u + 0x7FFFu + ((u >> 16) & 1u);
  return (unsigned short)(r >> 16);
}

__device__ __forceinline__ unsigned pk_bf16(float a, float b) {
  __hip_bfloat162 p = __float22bfloat162_rn(make_float2(a, b));
  return *(unsigned*)&p;
}

// Fused: emb fp32->bf16 (n8 uint4-groups) + W1t/W2t basis combine (transposed)
__global__ void prep_fused(const float* __restrict__ emb, unsigned short* __restrict__ embh,
                           int n8,
                           const float* __restrict__ comp1, const float* __restrict__ V1,
                           const float* __restrict__ comp2, const float* __restrict__ V2,
                           unsigned short* __restrict__ W1t, unsigned short* __restrict__ W2t) {
  int idx = blockIdx.x * blockDim.x + threadIdx.x;
  if (idx < n8) {
    float4 a = ((const float4*)emb)[idx * 2];
    float4 b = ((const float4*)emb)[idx * 2 + 1];
    uint4 o;
    o.x = pk_bf16(a.x, a.y);
    o.y = pk_bf16(a.z, a.w);
    o.z = pk_bf16(b.x, b.y);
    o.w = pk_bf16(b.z, b.w);
    ((uint4*)embh)[idx] = o;
    return;
  }
  int j = idx - n8;
  const int PER_R = HDIM * (HDIM + 64);  // 24576
  if (j >= RELS * PER_R) return;
  int r = j / PER_R;
  int rem = j - r * PER_R;
  if (rem < HDIM * HDIM) {
    int o = rem >> 7, k = rem & 127;
    float s = 0.f;
#pragma unroll
    for (int b = 0; b < RELS; b++)
      s = fmaf(comp1[r * RELS + b], V1[(size_t)b * HDIM * HDIM + (size_t)k * HDIM + o], s);
    W1t[(size_t)r * HDIM * HDIM + rem] = f2bf(s);
  } else {
    int rr = rem - HDIM * HDIM;
    int o = rr >> 7, k = rr & 127;
    float s = 0.f;
#pragma unroll
    for (int b = 0; b < RELS; b++)
      s = fmaf(comp2[r * RELS + b], V2[(size_t)b * HDIM * 64 + (size_t)k * 64 + o], s);
    W2t[(size_t)r * 64 * HDIM + rr] = f2bf(s);
  }
}

// direct global histogram: 1M atomics over 12512 counters (~80/counter)
__global__ void hist_bins(const int* __restrict__ dst, const int* __restrict__ etype,
                          int n, int* __restrict__ counts) {
  for (int i = blockIdx.x * blockDim.x + threadIdx.x; i < n; i += gridDim.x * blockDim.x)
    atomicAdd(&counts[(dst[i] >> 6) * RELS + etype[i]], 1);
}

// exclusive scan of counts padded to multiples of 16 (Hillis-Steele)
__global__ void scan_offsets(const int* __restrict__ counts, int* __restrict__ offsets, int nbins) {
  __shared__ int csum[256];
  const int t = threadIdx.x;
  const int CH = (nbins + 255) / 256;
  int lo = t * CH, hi = min(lo + CH, nbins);
  int s = 0;
  for (int i = lo; i < hi; i++) s += (counts[i] + 15) & ~15;
  csum[t] = s;
  __syncthreads();
#pragma unroll
  for (int d = 1; d < 256; d <<= 1) {
    int v = (t >= d) ? csum[t - d] : 0;
    __syncthreads();
    csum[t] += v;
    __syncthreads();
  }
  int run = (t == 0) ? 0 : csum[t - 1];
  for (int i = lo; i < hi; i++) {
    offsets[i] = run;
    run += (counts[i] + 15) & ~15;
  }
  if (lo < nbins && hi == nbins) offsets[nbins] = run;
}

// ebuf[p] = {src | dloc<<20, norm_bf16}; pad slots unwritten (all consumers
// guard by counts; proven in rounds 7-9).
__global__ void scatter_bins(const int* __restrict__ src, const int* __restrict__ dst,
                             const int* __restrict__ etype, const float* __restrict__ norm,
                             int n, const int* __restrict__ offsets, int* __restrict__ cursor,
                             uint2* __restrict__ ebuf) {
  for (int i = blockIdx.x * blockDim.x + threadIdx.x; i < n; i += gridDim.x * blockDim.x) {
    int d = dst[i];
    int b = (d >> 6) * RELS + etype[i];
    int p = offsets[b] + atomicAdd(&cursor[b], 1);
    ebuf[p] = make_uint2((unsigned)src[i] | ((unsigned)(d & 63) << 20),
                         (unsigned)f2bf(norm[i]));
  }
}

// One block owns 64 dst nodes; walks its 16 relation bins in 32-edge chunks.
// Single barrier/chunk; xs/pmat double-buffered. Phase k: prefetch ebuf(k+1);
// GEMM1(k) from xs[cb] -> wave-local ys (packed cvt); issue gathers(k+1);
// agg(k): pacc += pmat[cb] @ ys; write xs[cb^1] + handler pmat[cb^1]; barrier.
// Wave w owns out columns [w*OUT/4, +OUT/4).
template <int OUT, bool BF16_RELU_OUT>
__launch_bounds__(256, 3)
__global__ void rgcn_layer(const unsigned short* __restrict__ Xb,  // [N][128] bf16
                           const unsigned short* __restrict__ Wt,  // [R][OUT][128] bf16
                           const uint2* __restrict__ ebuf,
                           const int* __restrict__ offsets, const int* __restrict__ counts,
                           const float* __restrict__ bias, void* __restrict__ Hout,
                           int nNodes) {
  constexpr int NT = OUT / 64;  // 2 (OUT=128) or 1 (OUT=64)
  __shared__ __align__(16) unsigned short xs[2][CHUNK][136];     // gathered src rows
  __shared__ __align__(16) unsigned short ys[OUT][40];           // messages^T, wave-local cols
  __shared__ __align__(16) unsigned short pmat[2][DSTBLK][40];   // P[dloc][edge] = bf16(norm)

  const int t = threadIdx.x;
  const int w = t >> 6;
  const int lane = t & 63;
  const int quad = lane >> 4;
  const int l16 = lane & 15;
  const int r0 = t >> 4;     // gather rows r0, r0+16
  const int k8 = t & 15;     // gather 8-elem column piece
  const bool isHandler = (t & 7) == 0;
  const int myCol = t >> 3;  // handler-owned edge column (0..31, fixed)
  const int nodeBase = blockIdx.x * DSTBLK;
  const int binBase = blockIdx.x * RELS;
  const int colBase = w * (OUT / 4);

  // one-time zero (stale LDS may hold NaN bit patterns; 0 * NaN = NaN)
  for (int i = t; i < 2 * CHUNK * 136 / 8; i += 256) ((uint4*)xs)[i] = make_uint4(0, 0, 0, 0);
  for (int i = t; i < OUT * 40 / 8; i += 256) ((uint4*)ys)[i] = make_uint4(0, 0, 0, 0);
  for (int i = t; i < 2 * DSTBLK * 40 / 8; i += 256) ((uint4*)pmat)[i] = make_uint4(0, 0, 0, 0);

  f32x4 pacc[MT_P][NT] = {};  // persistent dst accumulator

  // first nonempty bin
  int bin = 0, base = 0, binEnd = 0, realEnd = 0;
  for (; bin < RELS; bin++) {
    base = offsets[binBase + bin];
    binEnd = offsets[binBase + bin + 1];
    if (base < binEnd) { realEnd = base + counts[binBase + bin]; break; }
  }

  __syncthreads();  // zero-init visible before prologue LDS writes

  // prologue: load chunk 0 into xs[0]/pmat[0] (full latency exposed once)
  int pdA = -1, pdB = -1;  // handler prev-entry trackers per buffer parity
  if (bin < RELS) {
    int nR = min(CHUNK, realEnd - base);
    if (r0 < nR) {
      uint2 e = ebuf[base + r0];
      *(uint4*)&xs[0][r0][k8 * 8] = *(const uint4*)(Xb + (size_t)(e.x & 0xFFFFFu) * HDIM + k8 * 8);
    }
    if (16 + r0 < nR) {
      uint2 e = ebuf[base + 16 + r0];
      *(uint4*)&xs[0][16 + r0][k8 * 8] = *(const uint4*)(Xb + (size_t)(e.x & 0xFFFFFu) * HDIM + k8 * 8);
    }
    if (isHandler && myCol < nR) {
      uint2 m = ebuf[base + myCol];
      int dl = (int)(m.x >> 20) & 63;
      pmat[0][dl][myCol] = (unsigned short)(m.y & 0xFFFFu);
      pdB = dl;  // buffer 0 is written again two phases from now
    }
  }
  __syncthreads();

  int cb = 0;
  int curRel = -1;
  bf16x8 wf[4][NT];

  while (bin < RELS) {
    const int nRows = min(CHUNK, realEnd - base);

    if (bin != curRel) {  // W fragments for this relation (register-resident)
      curRel = bin;
      const unsigned short* Wr = Wt + (size_t)bin * OUT * HDIM;
#pragma unroll
      for (int ks = 0; ks < 4; ks++)
#pragma unroll
        for (int nt = 0; nt < NT; nt++)
          wf[ks][nt] = *(const bf16x8*)(Wr + (size_t)(colBase + nt * 16 + l16) * HDIM + ks * 32 + quad * 8);
    }

    // next chunk coords (scalar)
    int nbin = bin, nbase = base + CHUNK, nbinEnd = binEnd, nrealEnd = realEnd;
    if (nbase >= binEnd) {
      for (nbin = bin + 1; nbin < RELS; nbin++) {
        nbase = offsets[binBase + nbin];
        nbinEnd = offsets[binBase + nbin + 1];
        if (nbase < nbinEnd) { nrealEnd = nbase + counts[binBase + nbin]; break; }
      }
    }
    const bool hasNext = nbin < RELS;
    const int nR = hasNext ? min(CHUNK, nrealEnd - nbase) : 0;

    // ---- prefetch next chunk's ebuf entries (latency under GEMM1) ----
    uint2 e0, e1, em;
    if (hasNext) {
      if (r0 < nR) e0 = ebuf[nbase + r0];
      if (16 + r0 < nR) e1 = ebuf[nbase + 16 + r0];
      if (isHandler && myCol < nR) em = ebuf[nbase + myCol];
    }

    // ---- GEMM1: Y = xs[cb] @ W_r -> wave-local ys^T (m = edge rows) ----
#pragma unroll
    for (int mt = 0; mt < 2; mt++) {
      if (mt * 16 < nRows) {  // wave-uniform
        f32x4 dacc[NT] = {};
#pragma unroll
        for (int ks = 0; ks < 4; ks++) {
          bf16x8 a = *(const bf16x8*)&xs[cb][mt * 16 + l16][ks * 32 + quad * 8];
#pragma unroll
          for (int nt = 0; nt < NT; nt++)
            dacc[nt] = __builtin_amdgcn_mfma_f32_16x16x32_bf16(a, wf[ks][nt], dacc[nt], 0, 0, 0);
        }
#pragma unroll
        for (int nt = 0; nt < NT; nt++) {
          uint2 pk;
          pk.x = pk_bf16(dacc[nt][0], dacc[nt][1]);
          pk.y = pk_bf16(dacc[nt][2], dacc[nt][3]);
          *(uint2*)&ys[colBase + nt * 16 + l16][mt * 16 + quad * 4] = pk;
        }
      }
    }

    // ---- issue next chunk's gathers (latency under agg) ----
    uint4 g0, g1;
    if (hasNext) {
      if (r0 < nR) g0 = *(const uint4*)(Xb + (size_t)(e0.x & 0xFFFFFu) * HDIM + k8 * 8);
      if (16 + r0 < nR) g1 = *(const uint4*)(Xb + (size_t)(e1.x & 0xFFFFFu) * HDIM + k8 * 8);
    }

    // ---- agg: pacc += pmat[cb] @ ys (k = 32 edges, single pass) ----
    // m = dst rows (ungated); pad edge-columns carry pmat == 0.
    {
      bf16x8 bfv[NT];
#pragma unroll
      for (int nt = 0; nt < NT; nt++)
        bfv[nt] = *(const bf16x8*)&ys[colBase + nt * 16 + l16][quad * 8];
#pragma unroll
      for (int mt = 0; mt < MT_P; mt++) {
        bf16x8 a = *(const bf16x8*)&pmat[cb][mt * 16 + l16][quad * 8];
#pragma unroll
        for (int nt = 0; nt < NT; nt++)
          pacc[mt][nt] = __builtin_amdgcn_mfma_f32_16x16x32_bf16(a, bfv[nt], pacc[mt][nt], 0, 0, 0);
      }
    }

    // ---- write next chunk into the other buffers, then barrier ----
    if (hasNext) {
      if (r0 < nR) *(uint4*)&xs[cb ^ 1][r0][k8 * 8] = g0;
      if (16 + r0 < nR) *(uint4*)&xs[cb ^ 1][16 + r0][k8 * 8] = g1;
      if (isHandler) {
        if (pdA >= 0) pmat[cb ^ 1][pdA][myCol] = 0;  // clear own old entry (same-lane order)
        if (myCol < nR) {
          int dl = (int)(em.x >> 20) & 63;
          pmat[cb ^ 1][dl][myCol] = (unsigned short)(em.y & 0xFFFFu);
          pdA = dl;
        } else {
          pdA = -1;
        }
      }
    }
    { int tmp = pdA; pdA = pdB; pdB = tmp; }  // tracker follows buffer parity

    if (hasNext) __syncthreads();  // block-uniform condition

    bin = nbin; base = nbase; binEnd = nbinEnd; realEnd = nrealEnd;
    cb ^= 1;
  }

  // epilogue: each (node, col) owned by exactly one lane -> plain stores
#pragma unroll
  for (int mt = 0; mt < MT_P; mt++) {
#pragma unroll
    for (int reg = 0; reg < 4; reg++) {
      int node = nodeBase + mt * 16 + quad * 4 + reg;
      if (node < nNodes) {
#pragma unroll
        for (int nt = 0; nt < NT; nt++) {
          int col = colBase + nt * 16 + l16;
          float v = pacc[mt][nt][reg] + bias[col];
          if constexpr (BF16_RELU_OUT)
            ((unsigned short*)Hout)[(size_t)node * OUT + col] = f2bf(fmaxf(v, 0.f));
          else
            ((float*)Hout)[(size_t)node * OUT + col] = v;
        }
      }
    }
  }
}

extern "C" void kernel_launch(void* const* d_in, const int* in_sizes, int n_in,
                              void* d_out, int out_size, void* d_ws, size_t ws_size,
                              hipStream_t stream) {
  const int*   src   = (const int*)d_in[1];
  const int*   dst   = (const int*)d_in[2];
  const int*   etype = (const int*)d_in[3];
  const float* norm  = (const float*)d_in[4];
  const float* emb   = (const float*)d_in[5];
  const float* V1    = (const float*)d_in[6];
  const float* comp1 = (const float*)d_in[7];
  const float* bias1 = (const float*)d_in[8];
  const float* V2    = (const float*)d_in[9];
  const float* comp2 = (const float*)d_in[10];
  const float* bias2 = (const float*)d_in[11];
  float* out = (float*)d_out;

  const int N = in_sizes[0];  // 50000
  const int E = in_sizes[1];  // 1000000
  const int H = 128, O = 64;
  const int NB = (N + DSTBLK - 1) / DSTBLK;  // 782
  const int NBINS = NB * RELS;               // 12512
  const int EPAD_MAX = E + NBINS * 16 + 64;

  char* ws = (char*)d_ws;
  size_t off = 0;
  auto alloc = [&](size_t bytes) -> void* {
    void* p = ws + off;
    off += (bytes + 255) & ~(size_t)255;
    return p;
  };
  unsigned short* W1t  = (unsigned short*)alloc(sizeof(short) * RELS * H * H);
  unsigned short* W2t  = (unsigned short*)alloc(sizeof(short) * RELS * O * H);
  unsigned short* embh = (unsigned short*)alloc(sizeof(short) * (size_t)N * H);
  unsigned short* h1b  = (unsigned short*)alloc(sizeof(short) * (size_t)N * H);
  uint2* ebuf = (uint2*)alloc(sizeof(uint2) * EPAD_MAX);
  int* cc      = (int*)alloc(sizeof(int) * 2 * NBINS);  // counts | cursor contiguous
  int* counts  = cc;
  int* cursor  = cc + NBINS;
  int* offsets = (int*)alloc(sizeof(int) * (NBINS + 1));

  hipMemsetAsync(cc, 0, sizeof(int) * 2 * NBINS, stream);

  const int n8 = N * H / 8;  // 800000
  prep_fused<<<(n8 + RELS * H * (H + O) + 255) / 256, 256, 0, stream>>>(
      emb, embh, n8, comp1, V1, comp2, V2, W1t, W2t);
  hist_bins<<<512, 256, 0, stream>>>(dst, etype, E, counts);
  scan_offsets<<<1, 256, 0, stream>>>(counts, offsets, NBINS);
  scatter_bins<<<1024, 256, 0, stream>>>(src, dst, etype, norm, E, offsets, cursor, ebuf);

  rgcn_layer<128, true><<<NB, 256, 0, stream>>>(embh, W1t, ebuf, offsets, counts, bias1, (void*)h1b, N);
  rgcn_layer<64, false><<<NB, 256, 0, stream>>>(h1b, W2t, ebuf, offsets, counts, bias2, (void*)out, N);
}

// Round 14
// 462.485 us; speedup vs baseline: 1.7686x; 1.0923x over previous
//
#include <hip/hip_runtime.h>
#include <hip/hip_bf16.h>

// ---------------------------------------------------------------------------
// RGCN (basis decomposition), 2 layers. N=50000, E=1e6, H=128, O=64, R=16.
// Round 14: fix the per-chunk exposed latency found in rounds 9/13's
// schedule: the chunk-(k+1) gather was issued AFTER GEMM1 (address depends
// on the ebuf entry loaded the same phase) -> only agg (~250cyc) covered a
// 300-900cyc gather. Changes:
//  - ebuf prefetch distance 2: hold 3 ebuf entries (6 VGPRs) across ONE
//    barrier; gathers for chunk k+1 issue at the TOP of phase k -> covered
//    by GEMM1+agg (~full phase). (Round 5's spill held 24+ VGPRs incl. all
//    gather data; 6 is cheap.)
//  - W-fragment prefetch: when the next chunk starts a new bin, wf reloads
//    between GEMM1(k) (last wf consumer) and agg(k) -> bin-transition W
//    loads get ~400cyc cover instead of 0.
//  - Geometry restored to round 9's proven best: DSTBLK 66 -> grid 758 <=
//    768 residency slots (3 blocks/CU @ 40448 B LDS), LDS-staged histogram.
//  - Keep round 13 wins: pk_bf16 (v_cvt_pk_bf16_f32) ys packing, norm as
//    bf16 in ebuf, fused cvt+compute_w, single memset, no ebuf memset.
// ---------------------------------------------------------------------------

typedef short bf16x8 __attribute__((ext_vector_type(8)));
typedef float f32x4 __attribute__((ext_vector_type(4)));

#define RELS 16
#define HDIM 128
#define DSTBLK 66
#define MT_P 5    // ceil(66/16): pmat has 80 rows
#define CHUNK 32
#define MAXBINS 12288

__device__ inline unsigned short f2bf(float f) {
  unsigned int u = __float_as_uint(f);
  unsigned int r = u + 0x7FFFu + ((u >> 16) & 1u);
  return (unsigned short)(r >> 16);
}

__device__ __forceinline__ unsigned pk_bf16(float a, float b) {
  __hip_bfloat162 p = __float22bfloat162_rn(make_float2(a, b));
  return *(unsigned*)&p;
}

// Fused: emb fp32->bf16 (n8 uint4-groups) + W1t/W2t basis combine (transposed)
__global__ void prep_fused(const float* __restrict__ emb, unsigned short* __restrict__ embh,
                           int n8,
                           const float* __restrict__ comp1, const float* __restrict__ V1,
                           const float* __restrict__ comp2, const float* __restrict__ V2,
                           unsigned short* __restrict__ W1t, unsigned short* __restrict__ W2t) {
  int idx = blockIdx.x * blockDim.x + threadIdx.x;
  if (idx < n8) {
    float4 a = ((const float4*)emb)[idx * 2];
    float4 b = ((const float4*)emb)[idx * 2 + 1];
    uint4 o;
    o.x = pk_bf16(a.x, a.y);
    o.y = pk_bf16(a.z, a.w);
    o.z = pk_bf16(b.x, b.y);
    o.w = pk_bf16(b.z, b.w);
    ((uint4*)embh)[idx] = o;
    return;
  }
  int j = idx - n8;
  const int PER_R = HDIM * (HDIM + 64);  // 24576
  if (j >= RELS * PER_R) return;
  int r = j / PER_R;
  int rem = j - r * PER_R;
  if (rem < HDIM * HDIM) {
    int o = rem >> 7, k = rem & 127;
    float s = 0.f;
#pragma unroll
    for (int b = 0; b < RELS; b++)
      s = fmaf(comp1[r * RELS + b], V1[(size_t)b * HDIM * HDIM + (size_t)k * HDIM + o], s);
    W1t[(size_t)r * HDIM * HDIM + rem] = f2bf(s);
  } else {
    int rr = rem - HDIM * HDIM;
    int o = rr >> 7, k = rr & 127;
    float s = 0.f;
#pragma unroll
    for (int b = 0; b < RELS; b++)
      s = fmaf(comp2[r * RELS + b], V2[(size_t)b * HDIM * 64 + (size_t)k * 64 + o], s);
    W2t[(size_t)r * 64 * HDIM + rr] = f2bf(s);
  }
}

// LDS-staged histogram (round-9 proven): few global atomics per bin
__global__ void hist_bins(const int* __restrict__ dst, const int* __restrict__ etype,
                          int n, int nbins, int* __restrict__ counts) {
  __shared__ int lh[MAXBINS];
  for (int j = threadIdx.x; j < nbins; j += blockDim.x) lh[j] = 0;
  __syncthreads();
  for (int i = blockIdx.x * blockDim.x + threadIdx.x; i < n; i += gridDim.x * blockDim.x)
    atomicAdd(&lh[(dst[i] / DSTBLK) * RELS + etype[i]], 1);
  __syncthreads();
  for (int j = threadIdx.x; j < nbins; j += blockDim.x) {
    int c = lh[j];
    if (c) atomicAdd(&counts[j], c);
  }
}

// exclusive scan of counts padded to multiples of 16 (Hillis-Steele)
__global__ void scan_offsets(const int* __restrict__ counts, int* __restrict__ offsets, int nbins) {
  __shared__ int csum[256];
  const int t = threadIdx.x;
  const int CH = (nbins + 255) / 256;
  int lo = t * CH, hi = min(lo + CH, nbins);
  int s = 0;
  for (int i = lo; i < hi; i++) s += (counts[i] + 15) & ~15;
  csum[t] = s;
  __syncthreads();
#pragma unroll
  for (int d = 1; d < 256; d <<= 1) {
    int v = (t >= d) ? csum[t - d] : 0;
    __syncthreads();
    csum[t] += v;
    __syncthreads();
  }
  int run = (t == 0) ? 0 : csum[t - 1];
  for (int i = lo; i < hi; i++) {
    offsets[i] = run;
    run += (counts[i] + 15) & ~15;
  }
  if (lo < nbins && hi == nbins) offsets[nbins] = run;
}

// ebuf[p] = {src | dloc<<20, norm_bf16}; pad slots unwritten (all consumers
// guard by counts; proven rounds 7-9/13).
__global__ void scatter_bins(const int* __restrict__ src, const int* __restrict__ dst,
                             const int* __restrict__ etype, const float* __restrict__ norm,
                             int n, const int* __restrict__ offsets, int* __restrict__ cursor,
                             uint2* __restrict__ ebuf) {
  for (int i = blockIdx.x * blockDim.x + threadIdx.x; i < n; i += gridDim.x * blockDim.x) {
    int d = dst[i];
    int blk = d / DSTBLK;
    int b = blk * RELS + etype[i];
    int p = offsets[b] + atomicAdd(&cursor[b], 1);
    ebuf[p] = make_uint2((unsigned)src[i] | ((unsigned)(d - blk * DSTBLK) << 20),
                         (unsigned)f2bf(norm[i]));
  }
}

// One block owns 66 dst nodes; walks its 16 relation bins in 32-edge chunks.
// Single barrier/chunk; xs/pmat double-buffered; ebuf prefetch DISTANCE 2
// (3 uint2 regs cross one barrier) so gathers issue at phase top. Phase k:
// gathers(k+1) issue; GEMM1(k); [wf reload if next bin differs]; ebuf(k+2)
// loads; agg(k); write xs/pmat[k+1]; barrier. Wave w owns cols [w*OUT/4,+OUT/4).
template <int OUT, bool BF16_RELU_OUT>
__launch_bounds__(256, 3)
__global__ void rgcn_layer(const unsigned short* __restrict__ Xb,  // [N][128] bf16
                           const unsigned short* __restrict__ Wt,  // [R][OUT][128] bf16
                           const uint2* __restrict__ ebuf,
                           const int* __restrict__ offsets, const int* __restrict__ counts,
                           const float* __restrict__ bias, void* __restrict__ Hout,
                           int nNodes) {
  constexpr int NT = OUT / 64;  // 2 (OUT=128) or 1 (OUT=64)
  __shared__ __align__(16) unsigned short xs[2][CHUNK][136];   // gathered src rows
  __shared__ __align__(16) unsigned short ys[OUT][40];         // messages^T, wave-local cols
  __shared__ __align__(16) unsigned short pmat[2][80][40];     // P[dloc][edge] = bf16(norm)

  const int t = threadIdx.x;
  const int w = t >> 6;
  const int lane = t & 63;
  const int quad = lane >> 4;
  const int l16 = lane & 15;
  const int r0 = t >> 4;     // gather rows r0, r0+16
  const int k8 = t & 15;     // gather 8-elem column piece
  const bool isHandler = (t & 7) == 0;
  const int myCol = t >> 3;  // handler-owned edge column (0..31, fixed)
  const int nodeBase = blockIdx.x * DSTBLK;
  const int binBase = blockIdx.x * RELS;
  const int colBase = w * (OUT / 4);

  // one-time zero (stale LDS may hold NaN bit patterns; 0 * NaN = NaN)
  for (int i = t; i < 2 * CHUNK * 136 / 8; i += 256) ((uint4*)xs)[i] = make_uint4(0, 0, 0, 0);
  for (int i = t; i < OUT * 40 / 8; i += 256) ((uint4*)ys)[i] = make_uint4(0, 0, 0, 0);
  for (int i = t; i < 2 * 80 * 40 / 8; i += 256) ((uint4*)pmat)[i] = make_uint4(0, 0, 0, 0);

  f32x4 pacc[MT_P][NT] = {};  // persistent dst accumulator

  // chunk walker: returns first chunk at/after (bin,base)
  // cur = chunk k; nxt = chunk k+1
  int cBin = 0, cBase = 0, cBinEnd = 0, cRealEnd = 0;
  for (; cBin < RELS; cBin++) {
    cBase = offsets[binBase + cBin];
    cBinEnd = offsets[binBase + cBin + 1];
    if (cBase < cBinEnd) { cRealEnd = cBase + counts[binBase + cBin]; break; }
  }
  int nBin = cBin, nBase = cBase + CHUNK, nBinEnd = cBinEnd, nRealEnd = cRealEnd;
  if (cBin < RELS && nBase >= cBinEnd) {
    for (nBin = cBin + 1; nBin < RELS; nBin++) {
      nBase = offsets[binBase + nBin];
      nBinEnd = offsets[binBase + nBin + 1];
      if (nBase < nBinEnd) { nRealEnd = nBase + counts[binBase + nBin]; break; }
    }
  }

  __syncthreads();  // zero-init visible before prologue LDS writes

  // prologue: chunk 0 into xs[0]/pmat[0] (latency exposed once);
  // ebuf entries for chunk 1 into registers (cross the barrier: 6 VGPRs).
  int pdA = -1, pdB = -1;  // handler prev-entry trackers per buffer parity
  uint2 eC0, eC1, eCm;     // ebuf entries for chunk k+1 (held across barrier)
  if (cBin < RELS) {
    int nR = min(CHUNK, cRealEnd - cBase);
    if (r0 < nR) {
      uint2 e = ebuf[cBase + r0];
      *(uint4*)&xs[0][r0][k8 * 8] = *(const uint4*)(Xb + (size_t)(e.x & 0xFFFFFu) * HDIM + k8 * 8);
    }
    if (16 + r0 < nR) {
      uint2 e = ebuf[cBase + 16 + r0];
      *(uint4*)&xs[0][16 + r0][k8 * 8] = *(const uint4*)(Xb + (size_t)(e.x & 0xFFFFFu) * HDIM + k8 * 8);
    }
    if (isHandler && myCol < nR) {
      uint2 m = ebuf[cBase + myCol];
      int dl = (int)(m.x >> 20) & 127;
      pmat[0][dl][myCol] = (unsigned short)(m.y & 0xFFFFu);
      pdB = dl;  // buffer 0 written again two phases out
    }
    if (nBin < RELS) {  // prefetch chunk-1 ebuf entries
      int nR1 = min(CHUNK, nRealEnd - nBase);
      if (r0 < nR1) eC0 = ebuf[nBase + r0];
      if (16 + r0 < nR1) eC1 = ebuf[nBase + 16 + r0];
      if (isHandler && myCol < nR1) eCm = ebuf[nBase + myCol];
    }
  }

  // W fragments for chunk 0's bin (exposed once)
  bf16x8 wf[4][NT];
  if (cBin < RELS) {
    const unsigned short* Wr = Wt + (size_t)cBin * OUT * HDIM;
#pragma unroll
    for (int ks = 0; ks < 4; ks++)
#pragma unroll
      for (int nt = 0; nt < NT; nt++)
        wf[ks][nt] = *(const bf16x8*)(Wr + (size_t)(colBase + nt * 16 + l16) * HDIM + ks * 32 + quad * 8);
  }
  __syncthreads();

  int cb = 0;
  while (cBin < RELS) {
    const int nRows = min(CHUNK, cRealEnd - cBase);
    const bool hasNext = nBin < RELS;
    const int nR1 = hasNext ? min(CHUNK, nRealEnd - nBase) : 0;

    // ---- issue gathers for chunk k+1 at PHASE TOP (addresses already in
    //      registers from last phase) -> covered by GEMM1 + agg ----
    uint4 g0, g1;
    if (hasNext) {
      if (r0 < nR1) g0 = *(const uint4*)(Xb + (size_t)(eC0.x & 0xFFFFFu) * HDIM + k8 * 8);
      if (16 + r0 < nR1) g1 = *(const uint4*)(Xb + (size_t)(eC1.x & 0xFFFFFu) * HDIM + k8 * 8);
    }

    // ---- GEMM1: Y = xs[cb] @ W_r -> wave-local ys^T (m = edge rows) ----
#pragma unroll
    for (int mt = 0; mt < 2; mt++) {
      if (mt * 16 < nRows) {  // wave-uniform
        f32x4 dacc[NT] = {};
#pragma unroll
        for (int ks = 0; ks < 4; ks++) {
          bf16x8 a = *(const bf16x8*)&xs[cb][mt * 16 + l16][ks * 32 + quad * 8];
#pragma unroll
          for (int nt = 0; nt < NT; nt++)
            dacc[nt] = __builtin_amdgcn_mfma_f32_16x16x32_bf16(a, wf[ks][nt], dacc[nt], 0, 0, 0);
        }
#pragma unroll
        for (int nt = 0; nt < NT; nt++) {
          uint2 pk;
          pk.x = pk_bf16(dacc[nt][0], dacc[nt][1]);
          pk.y = pk_bf16(dacc[nt][2], dacc[nt][3]);
          *(uint2*)&ys[colBase + nt * 16 + l16][mt * 16 + quad * 4] = pk;
        }
      }
    }

    // ---- wf prefetch: wf is dead until GEMM1(k+1); reload now if the next
    //      chunk starts a new bin (cover = agg + writes + barrier) ----
    if (hasNext && nBin != cBin) {
      const unsigned short* Wr = Wt + (size_t)nBin * OUT * HDIM;
#pragma unroll
      for (int ks = 0; ks < 4; ks++)
#pragma unroll
        for (int nt = 0; nt < NT; nt++)
          wf[ks][nt] = *(const bf16x8*)(Wr + (size_t)(colBase + nt * 16 + l16) * HDIM + ks * 32 + quad * 8);
    }

    // ---- chunk k+2 coords + its ebuf entries (cover = agg) ----
    int n2Bin = nBin, n2Base = nBase + CHUNK, n2BinEnd = nBinEnd, n2RealEnd = nRealEnd;
    if (hasNext && n2Base >= nBinEnd) {
      for (n2Bin = nBin + 1; n2Bin < RELS; n2Bin++) {
        n2Base = offsets[binBase + n2Bin];
        n2BinEnd = offsets[binBase + n2Bin + 1];
        if (n2Base < n2BinEnd) { n2RealEnd = n2Base + counts[binBase + n2Bin]; break; }
      }
    }
    uint2 en0, en1, enm;
    if (hasNext && n2Bin < RELS) {
      int nR2 = min(CHUNK, n2RealEnd - n2Base);
      if (r0 < nR2) en0 = ebuf[n2Base + r0];
      if (16 + r0 < nR2) en1 = ebuf[n2Base + 16 + r0];
      if (isHandler && myCol < nR2) enm = ebuf[n2Base + myCol];
    }

    // ---- agg: pacc += pmat[cb] @ ys (k = 32 edges, single pass) ----
    {
      bf16x8 bfv[NT];
#pragma unroll
      for (int nt = 0; nt < NT; nt++)
        bfv[nt] = *(const bf16x8*)&ys[colBase + nt * 16 + l16][quad * 8];
#pragma unroll
      for (int mt = 0; mt < MT_P; mt++) {
        bf16x8 a = *(const bf16x8*)&pmat[cb][mt * 16 + l16][quad * 8];
#pragma unroll
        for (int nt = 0; nt < NT; nt++)
          pacc[mt][nt] = __builtin_amdgcn_mfma_f32_16x16x32_bf16(a, bfv[nt], pacc[mt][nt], 0, 0, 0);
      }
    }

    // ---- write chunk k+1 into the other buffers, then barrier ----
    if (hasNext) {
      if (r0 < nR1) *(uint4*)&xs[cb ^ 1][r0][k8 * 8] = g0;
      if (16 + r0 < nR1) *(uint4*)&xs[cb ^ 1][16 + r0][k8 * 8] = g1;
      if (isHandler) {
        if (pdA >= 0) pmat[cb ^ 1][pdA][myCol] = 0;  // clear own old entry
        if (myCol < nR1) {
          int dl = (int)(eCm.x >> 20) & 127;
          pmat[cb ^ 1][dl][myCol] = (unsigned short)(eCm.y & 0xFFFFu);
          pdA = dl;
        } else {
          pdA = -1;
        }
      }
    }
    { int tmp = pdA; pdA = pdB; pdB = tmp; }  // tracker follows buffer parity

    if (hasNext) __syncthreads();  // block-uniform condition

    // shift pipeline state
    cBin = nBin; cBase = nBase; cBinEnd = nBinEnd; cRealEnd = nRealEnd;
    nBin = n2Bin; nBase = n2Base; nBinEnd = n2BinEnd; nRealEnd = n2RealEnd;
    eC0 = en0; eC1 = en1; eCm = enm;
    cb ^= 1;
  }

  // epilogue: each (node, col) owned by exactly one lane -> plain stores
#pragma unroll
  for (int mt = 0; mt < MT_P; mt++) {
#pragma unroll
    for (int reg = 0; reg < 4; reg++) {
      int ld = mt * 16 + quad * 4 + reg;
      int node = nodeBase + ld;
      if (ld < DSTBLK && node < nNodes) {
#pragma unroll
        for (int nt = 0; nt < NT; nt++) {
          int col = colBase + nt * 16 + l16;
          float v = pacc[mt][nt][reg] + bias[col];
          if constexpr (BF16_RELU_OUT)
            ((unsigned short*)Hout)[(size_t)node * OUT + col] = f2bf(fmaxf(v, 0.f));
          else
            ((float*)Hout)[(size_t)node * OUT + col] = v;
        }
      }
    }
  }
}

extern "C" void kernel_launch(void* const* d_in, const int* in_sizes, int n_in,
                              void* d_out, int out_size, void* d_ws, size_t ws_size,
                              hipStream_t stream) {
  const int*   src   = (const int*)d_in[1];
  const int*   dst   = (const int*)d_in[2];
  const int*   etype = (const int*)d_in[3];
  const float* norm  = (const float*)d_in[4];
  const float* emb   = (const float*)d_in[5];
  const float* V1    = (const float*)d_in[6];
  const float* comp1 = (const float*)d_in[7];
  const float* bias1 = (const float*)d_in[8];
  const float* V2    = (const float*)d_in[9];
  const float* comp2 = (const float*)d_in[10];
  const float* bias2 = (const float*)d_in[11];
  float* out = (float*)d_out;

  const int N = in_sizes[0];  // 50000
  const int E = in_sizes[1];  // 1000000
  const int H = 128, O = 64;
  const int NB = (N + DSTBLK - 1) / DSTBLK;  // 758
  const int NBINS = NB * RELS;               // 12128
  const int EPAD_MAX = E + NBINS * 16 + 64;

  char* ws = (char*)d_ws;
  size_t off = 0;
  auto alloc = [&](size_t bytes) -> void* {
    void* p = ws + off;
    off += (bytes + 255) & ~(size_t)255;
    return p;
  };
  unsigned short* W1t  = (unsigned short*)alloc(sizeof(short) * RELS * H * H);
  unsigned short* W2t  = (unsigned short*)alloc(sizeof(short) * RELS * O * H);
  unsigned short* embh = (unsigned short*)alloc(sizeof(short) * (size_t)N * H);
  unsigned short* h1b  = (unsigned short*)alloc(sizeof(short) * (size_t)N * H);
  uint2* ebuf = (uint2*)alloc(sizeof(uint2) * EPAD_MAX);
  int* cc      = (int*)alloc(sizeof(int) * 2 * NBINS);  // counts | cursor contiguous
  int* counts  = cc;
  int* cursor  = cc + NBINS;
  int* offsets = (int*)alloc(sizeof(int) * (NBINS + 1));

  hipMemsetAsync(cc, 0, sizeof(int) * 2 * NBINS, stream);

  const int n8 = N * H / 8;  // 800000
  prep_fused<<<(n8 + RELS * H * (H + O) + 255) / 256, 256, 0, stream>>>(
      emb, embh, n8, comp1, V1, comp2, V2, W1t, W2t);
  hist_bins<<<256, 256, 0, stream>>>(dst, etype, E, NBINS, counts);
  scan_offsets<<<1, 256, 0, stream>>>(counts, offsets, NBINS);
  scatter_bins<<<1024, 256, 0, stream>>>(src, dst, etype, norm, E, offsets, cursor, ebuf);

  rgcn_layer<128, true><<<NB, 256, 0, stream>>>(embh, W1t, ebuf, offsets, counts, bias1, (void*)h1b, N);
  rgcn_layer<64, false><<<NB, 256, 0, stream>>>(h1b, W2t, ebuf, offsets, counts, bias2, (void*)out, N);
}